// Round 3
// baseline (699.393 us; speedup 1.0000x reference)
//
#include <hip/hip_runtime.h>

typedef __attribute__((ext_vector_type(8))) short short8;
typedef __attribute__((ext_vector_type(4))) float float4_t;
typedef unsigned short u16;

#define K_DIM 768

__device__ __forceinline__ u16 f2bf(float f) {
  union { float f; unsigned u; } v; v.f = f;
  unsigned r = v.u + 0x7FFFu + ((v.u >> 16) & 1u);
  return (u16)(r >> 16);
}

__device__ __forceinline__ u16 f2bf_trunc(float f) {
  union { float f; unsigned u; } v; v.f = f;
  return (u16)(v.u >> 16);
}

__device__ __forceinline__ void gload16(const void* g, void* l) {
  __builtin_amdgcn_global_load_lds(
      (__attribute__((address_space(1))) void*)g,
      (__attribute__((address_space(3))) void*)l, 16, 0, 0);
}

// ---------------- fused fp32->bf16 converts + bank re-layout ----------------
__global__ __launch_bounds__(256) void cvt_all_kernel(
    const float* __restrict__ x, const float* __restrict__ qw,
    const float* __restrict__ pw, const float* __restrict__ bkf,
    const float* __restrict__ bvf,
    u16* __restrict__ xbf, u16* __restrict__ qwbf, u16* __restrict__ pwbf,
    u16* __restrict__ bk, u16* __restrict__ bvt) {
  const int blk = blockIdx.x;
  if (blk < 14592) {
    int i = blk * 256 + threadIdx.x;
    const float* src; u16* dst;
    if (i < 3145728)      { src = x;  dst = xbf; }
    else if (i < 3588096) { src = qw; dst = qwbf; i -= 3145728; }
    else                  { src = pw; dst = pwbf; i -= 3588096; }
    float4 v = ((const float4*)src)[i];
    union { u16 h[4]; unsigned long long ll; } o;
    o.h[0] = f2bf(v.x); o.h[1] = f2bf(v.y); o.h[2] = f2bf(v.z); o.h[3] = f2bf(v.w);
    ((unsigned long long*)dst)[i] = o.ll;
  } else {
    int idx = (blk - 14592) * 256 + threadIdx.x;  // < 196608
    int m = idx / 768;
    int c = idx - m * 768;
    int h = c >> 6, d = c & 63;
    bk[(h * 256 + m) * 64 + d] = f2bf(bkf[idx]);
    bvt[(h * 64 + d) * 256 + m] = f2bf(bvf[idx]);
  }
}

// ---------------- 256x256x64 8-phase bf16 GEMM, C = A * B^T ----------------
// (unchanged this round; its counters surface next round once fa drops)

#define SBAR()                                 \
  do {                                         \
    __builtin_amdgcn_sched_barrier(0);         \
    __builtin_amdgcn_s_barrier();              \
    __builtin_amdgcn_sched_barrier(0);         \
  } while (0)

#define VMW2()                                                  \
  do {                                                          \
    __builtin_amdgcn_sched_barrier(0);                          \
    asm volatile("s_waitcnt vmcnt(2)" ::: "memory");            \
  } while (0)

#define VMW0()                                                  \
  do {                                                          \
    __builtin_amdgcn_sched_barrier(0);                          \
    asm volatile("s_waitcnt vmcnt(0)" ::: "memory");            \
  } while (0)

#define LDA(B_, MH)                                                            \
  _Pragma("unroll") for (int m_ = 0; m_ < 4; m_++) {                           \
    const char* p_ =                                                           \
        (const char*)As[B_] + ((wm * 128 + (MH) * 64 + m_ * 16) << 7);         \
    af[m_][0] = *(const short8*)(p_ + ab0);                                    \
    af[m_][1] = *(const short8*)(p_ + ab1);                                    \
  }

#define LDB(B_, NH, BF)                                                        \
  _Pragma("unroll") for (int n_ = 0; n_ < 2; n_++) {                           \
    const char* p_ =                                                           \
        (const char*)Bs[B_] + ((wn * 64 + (NH) * 32 + n_ * 16) << 7);          \
    BF[n_][0] = *(const short8*)(p_ + ab0);                                    \
    BF[n_][1] = *(const short8*)(p_ + ab1);                                    \
  }

#define MFMAQ(MH, NH, BF)                                                      \
  do {                                                                         \
    __builtin_amdgcn_s_setprio(1);                                             \
    _Pragma("unroll") for (int m_ = 0; m_ < 4; m_++)                           \
        _Pragma("unroll") for (int n_ = 0; n_ < 2; n_++) {                     \
      acc[(MH) * 4 + m_][(NH) * 2 + n_] =                                      \
          __builtin_amdgcn_mfma_f32_16x16x32_bf16(                             \
              af[m_][0], BF[n_][0], acc[(MH) * 4 + m_][(NH) * 2 + n_], 0, 0,   \
              0);                                                              \
      acc[(MH) * 4 + m_][(NH) * 2 + n_] =                                      \
          __builtin_amdgcn_mfma_f32_16x16x32_bf16(                             \
              af[m_][1], BF[n_][1], acc[(MH) * 4 + m_][(NH) * 2 + n_], 0, 0,   \
              0);                                                              \
    }                                                                          \
    __builtin_amdgcn_s_setprio(0);                                             \
  } while (0)

template <int MODE>
__global__ __launch_bounds__(512, 2) void gemm256(
    const u16* __restrict__ A, const u16* __restrict__ Bw,
    const float* __restrict__ bias,
    u16* __restrict__ q_ws, u16* __restrict__ k_ws, u16* __restrict__ vt_ws,
    float* __restrict__ p_out) {
  __shared__ u16 As[2][16384];   // [buf][256 rows x 64 cols], 128B rows
  __shared__ u16 Bs[2][16384];
  const int tid = threadIdx.x;
  const int w = tid >> 6, lane = tid & 63;
  const int l15 = lane & 15, quad = lane >> 4;
  const int wm = w >> 2, wn = w & 3;

  constexpr int NBN = (MODE == 0) ? 9 : 3;
  const int bid = blockIdx.x;
  const int xcd = bid & 7, local = bid >> 3;   // nwg % 8 == 0 -> bijective
  const int bm = xcd * 8 + local / NBN;
  const int bn = local % NBN;

  // staging constants: linear LDS dest + inverse-swizzled global source.
  int soff[2], loff[2];
#pragma unroll
  for (int r = 0; r < 2; r++) {
    const int off = r * 8192 + tid * 16;     // byte in 16KB unit
    const int row = off >> 7;                // 128B per row (64 bf16)
    const int grp = (off & 127) >> 4;        // phys 16B slot 0..7
    soff[r] = row * K_DIM + ((grp ^ (row & 7)) * 8);
    loff[r] = off;
  }
  const u16* Abase = A + (size_t)bm * 256 * K_DIM;
  const u16* Bbase = Bw + (size_t)bn * 256 * K_DIM;

  auto stg = [&](const u16* g0, u16* l0) {
    gload16(g0 + soff[0], (char*)l0 + loff[0]);
    gload16(g0 + soff[1], (char*)l0 + loff[1]);
  };

  // ds-read swizzle constants: row&7 == l15&7 for all frag rows.
  const int ab0 = l15 * 128 + (((0 * 4 + quad) ^ (l15 & 7)) << 4);
  const int ab1 = l15 * 128 + (((1 * 4 + quad) ^ (l15 & 7)) << 4);

  float4_t acc[8][4];
#pragma unroll
  for (int i = 0; i < 8; i++)
#pragma unroll
    for (int j = 0; j < 4; j++) acc[i][j] = (float4_t){0.f, 0.f, 0.f, 0.f};

  short8 af[4][2], bf0[2][2], bf1[2][2];

  // ---- prologue: tile0 all 4 units + tile1 A0; wait tile0 ----
  stg(Abase, &As[0][0]);
  stg(Abase + 128 * K_DIM, &As[0][8192]);
  stg(Bbase, &Bs[0][0]);
  stg(Bbase + 128 * K_DIM, &Bs[0][8192]);
  stg(Abase + 64, &As[1][0]);
  VMW2();
  SBAR();

  // ---- main loop: groups 0..4, tiles 2g (buf0) and 2g+1 (buf1) ----
#pragma unroll 1
  for (int g = 0; g < 5; g++) {
    const int kt_o = g * 128 + 64;
    const int kt_p = g * 128 + 128;
    const int kt_q = g * 128 + 192;
    // P1: quadrant (mh0,nh0) of even tile; stage odd A1
    LDA(0, 0); LDB(0, 0, bf0);
    stg(Abase + 128 * K_DIM + kt_o, &As[1][8192]);
    SBAR(); MFMAQ(0, 0, bf0); SBAR();
    // P2: (mh0,nh1); stage odd B0
    LDB(0, 1, bf1);
    stg(Bbase + kt_o, &Bs[1][0]);
    SBAR(); MFMAQ(0, 1, bf1); SBAR();
    // P3: (mh1,nh1); stage odd B1   [last ds_read of buf0]
    LDA(0, 1);
    stg(Bbase + 128 * K_DIM + kt_o, &Bs[1][8192]);
    SBAR(); MFMAQ(1, 1, bf1); SBAR();
    // P4: (mh1,nh0); stage tile p A0 into buf0; wait odd tile complete
    stg(Abase + kt_p, &As[0][0]);
    VMW2(); SBAR(); MFMAQ(1, 0, bf0); SBAR();
    // P5: odd tile (mh0,nh0); stage p A1
    LDA(1, 0); LDB(1, 0, bf0);
    stg(Abase + 128 * K_DIM + kt_p, &As[0][8192]);
    SBAR(); MFMAQ(0, 0, bf0); SBAR();
    // P6: (mh0,nh1); stage p B0
    LDB(1, 1, bf1);
    stg(Bbase + kt_p, &Bs[0][0]);
    SBAR(); MFMAQ(0, 1, bf1); SBAR();
    // P7: (mh1,nh1); stage p B1   [last ds_read of buf1]
    LDA(1, 1);
    stg(Bbase + 128 * K_DIM + kt_p, &Bs[0][8192]);
    SBAR(); MFMAQ(1, 1, bf1); SBAR();
    // P8: (mh1,nh0); stage tile q A0 into buf1; wait tile p complete
    stg(Abase + kt_q, &As[1][0]);
    VMW2(); SBAR(); MFMAQ(1, 0, bf0); SBAR();
  }

  // ---- peeled last group: tiles 10 (buf0) and 11 (buf1) ----
  {
    const int kt_o = 704;
    LDA(0, 0); LDB(0, 0, bf0);
    stg(Abase + 128 * K_DIM + kt_o, &As[1][8192]);
    SBAR(); MFMAQ(0, 0, bf0); SBAR();
    LDB(0, 1, bf1);
    stg(Bbase + kt_o, &Bs[1][0]);
    SBAR(); MFMAQ(0, 1, bf1); SBAR();
    LDA(0, 1);
    stg(Bbase + 128 * K_DIM + kt_o, &Bs[1][8192]);
    SBAR(); MFMAQ(1, 1, bf1); SBAR();
    VMW0(); SBAR(); MFMAQ(1, 0, bf0); SBAR();
    LDA(1, 0); LDB(1, 0, bf0);
    SBAR(); MFMAQ(0, 0, bf0); SBAR();
    LDB(1, 1, bf1);
    SBAR(); MFMAQ(0, 1, bf1); SBAR();
    LDA(1, 1);
    SBAR(); MFMAQ(1, 1, bf1); SBAR();
    MFMAQ(1, 0, bf0);
  }

  // ---- epilogue ----
  const float QS = 0.18033688011112042f;  // (1/8) * log2(e)
#pragma unroll
  for (int mi = 0; mi < 8; mi++) {
#pragma unroll
    for (int ni = 0; ni < 4; ni++) {
      const int row0 = bm * 256 + wm * 128 + mi * 16 + quad * 4;
      const int f = bn * 256 + wn * 64 + ni * 16 + l15;
      const float bv = bias[f];
      if (MODE == 0) {
        const int which = f / 768;
        const int rem = f - which * 768;
        const int h = rem >> 6, d = rem & 63;
#pragma unroll
        for (int r2 = 0; r2 < 4; r2++) {
          float v = acc[mi][ni][r2] + bv;
          const int i = row0 + r2;
          const int bb = i >> 10, n = i & 1023;
          const size_t bhh = (size_t)(bb * 12 + h);
          if (which == 0)      q_ws[(bhh * 1024 + n) * 64 + d] = f2bf(v * QS);
          else if (which == 1) k_ws[(bhh * 1024 + n) * 64 + d] = f2bf(v);
          else                 vt_ws[(bhh * 64 + d) * 1024 + n] = f2bf(v);
        }
      } else {
#pragma unroll
        for (int r2 = 0; r2 < 4; r2++) {
          const int i = row0 + r2;
          p_out[(size_t)i * 768 + f] = acc[mi][ni][r2] + bv;
        }
      }
    }
  }
}

// ---------------- flash attention, double-buffered staging ----------------
// LDS 32 KB: smem[2][8192] = two K/V buffers (Ks 8KB + Vts 8KB each).
// Per iter t (cur = t&1): issue stage(t+1 -> cur^1) FIRST (stays in flight
// across the mid-barrier); compute QK from cur; pull V frags to regs;
// raw barrier + lgkmcnt(0) ONLY (no vmcnt drain!) -> P tiles alias cur's
// region (dead after kf/vf in regs); softmax+PV; end barrier with vmcnt(0)
// (staging loads had the whole iteration to land -> latency hidden).
__global__ __launch_bounds__(256, 4) void fa_kernel(
    const u16* __restrict__ qws, const u16* __restrict__ kws,
    const u16* __restrict__ vtws, const u16* __restrict__ bk,
    const u16* __restrict__ bvt,
    float* __restrict__ out, u16* __restrict__ obf) {
  __shared__ u16 smem[2][8192];      // 32 KB double buffer

  const int tid = threadIdx.x;
  const int w = tid >> 6, lane = tid & 63;
  const int l15 = lane & 15, quad = lane >> 4;
  const int bh = blockIdx.x;
  const int b = bh / 12, h = bh - b * 12;
  const int q0 = blockIdx.y * 128 + w * 32;

  short8 qf[2][2];
  {
    const u16* qb = qws + ((size_t)bh * 1024 + q0) * 64;
#pragma unroll
    for (int rt = 0; rt < 2; rt++)
#pragma unroll
      for (int c = 0; c < 2; c++)
        qf[rt][c] = *(const short8*)(qb + (rt * 16 + l15) * 64 + c * 32 + quad * 8);
  }

  const short ONE = (short)0x3F80;  // bf16 1.0
  const short8 onesf = (short8){ONE, ONE, ONE, ONE, ONE, ONE, ONE, ONE};

  float4_t O[2][4];
  float4_t lacc[2];
#pragma unroll
  for (int rt = 0; rt < 2; rt++) {
#pragma unroll
    for (int dt = 0; dt < 4; dt++) O[rt][dt] = (float4_t){0.f, 0.f, 0.f, 0.f};
    lacc[rt] = (float4_t){0.f, 0.f, 0.f, 0.f};
  }

  auto stage = [&](int tt, int buf) {
    const int mb = tt * 64;
    u16* Ksb = &smem[buf][0];
    u16* Vtb = &smem[buf][4096];
#pragma unroll
    for (int r = 0; r < 2; r++) {
      const int off = (w * 2 + r) * 1024 + lane * 16;
      const int row = off >> 7;             // 128B per row (64 bf16)
      const int grp = (off & 127) >> 4;     // 0..7
      const int lcol = (grp ^ (row & 7)) * 8;
      const u16* g = (mb < 1024)
          ? kws + ((size_t)bh * 1024 + mb + row) * 64 + lcol
          : bk + ((size_t)h * 256 + (mb - 1024) + row) * 64 + lcol;
      gload16(g, (char*)Ksb + off);
      const u16* g2 = (mb < 1024)
          ? vtws + ((size_t)bh * 64 + row) * 1024 + mb + lcol
          : bvt + ((size_t)h * 64 + row) * 256 + (mb - 1024) + lcol;
      gload16(g2, (char*)Vtb + off);
    }
  };

  // prologue: stage tile 0 into buf 0
  stage(0, 0);
  __builtin_amdgcn_sched_barrier(0);
  asm volatile("s_waitcnt vmcnt(0)" ::: "memory");
  __builtin_amdgcn_s_barrier();
  __builtin_amdgcn_sched_barrier(0);

#pragma unroll 1
  for (int t = 0; t < 20; t++) {
    const int cur = t & 1;
    // async prefetch of next K/V tile into the other buffer
    if (t < 19) stage(t + 1, cur ^ 1);

    const u16* Ks  = &smem[cur][0];
    const u16* Vts = &smem[cur][4096];
    u16* Psw = &smem[cur][0] + w * 2048;   // per-wave P tile, aliases cur

    short8 kf[4][2];
#pragma unroll
    for (int ct = 0; ct < 4; ct++)
#pragma unroll
      for (int c = 0; c < 2; c++) {
        const int row = ct * 16 + l15;
        kf[ct][c] = *(const short8*)(Ks + row * 64 + ((c * 4 + quad) ^ (row & 7)) * 8);
      }

    float4_t S[2][4];
#pragma unroll
    for (int rt = 0; rt < 2; rt++)
#pragma unroll
      for (int ct = 0; ct < 4; ct++) {
        float4_t z = (float4_t){0.f, 0.f, 0.f, 0.f};
        z = __builtin_amdgcn_mfma_f32_16x16x32_bf16(qf[rt][0], kf[ct][0], z, 0, 0, 0);
        S[rt][ct] = __builtin_amdgcn_mfma_f32_16x16x32_bf16(qf[rt][1], kf[ct][1], z, 0, 0, 0);
      }

    // V fragments into registers BEFORE P overwrites the cur region
    short8 vf[4][2];
#pragma unroll
    for (int dt = 0; dt < 4; dt++)
#pragma unroll
      for (int c = 0; c < 2; c++) {
        const int row = dt * 16 + l15;
        vf[dt][c] = *(const short8*)(Vts + row * 64 + ((c * 4 + quad) ^ (row & 7)) * 8);
      }

    // mid barrier: all waves' K/V reads of cur retired; staging loads
    // (vmcnt) deliberately NOT drained -> stay in flight.
    __builtin_amdgcn_sched_barrier(0);
    asm volatile("s_waitcnt lgkmcnt(0)" ::: "memory");
    __builtin_amdgcn_s_barrier();
    __builtin_amdgcn_sched_barrier(0);

    // exp2 + truncating bf16 pack -> aliased LDS (per-wave region)
#pragma unroll
    for (int rt = 0; rt < 2; rt++) {
#pragma unroll
      for (int ct = 0; ct < 4; ct++) {
        const int colg = ct * 2 + (l15 >> 3);
#pragma unroll
        for (int r = 0; r < 4; r++) {
          const float p = __builtin_amdgcn_exp2f(S[rt][ct][r]);
          const int q = rt * 16 + quad * 4 + r;
          Psw[q * 64 + (colg ^ (q & 7)) * 8 + (l15 & 7)] = f2bf_trunc(p);
        }
      }
    }

#pragma unroll
    for (int rt = 0; rt < 2; rt++)
#pragma unroll
      for (int c = 0; c < 2; c++) {
        const int qrow = rt * 16 + l15;
        const short8 pf = *(const short8*)(&Psw[qrow * 64 + (((c * 4 + quad) ^ (qrow & 7)) * 8)]);
#pragma unroll
        for (int dt = 0; dt < 4; dt++)
          O[rt][dt] = __builtin_amdgcn_mfma_f32_16x16x32_bf16(pf, vf[dt][c], O[rt][dt], 0, 0, 0);
        lacc[rt] = __builtin_amdgcn_mfma_f32_16x16x32_bf16(pf, onesf, lacc[rt], 0, 0, 0);
      }

    // end barrier: own staging loads landed (full iter to fly) + all P
    // writes/reads retired before next iter stages over this region.
    __builtin_amdgcn_sched_barrier(0);
    asm volatile("s_waitcnt vmcnt(0) lgkmcnt(0)" ::: "memory");
    __builtin_amdgcn_s_barrier();
    __builtin_amdgcn_sched_barrier(0);
  }

#pragma unroll
  for (int rt = 0; rt < 2; rt++) {
    float rl[4];
#pragma unroll
    for (int r = 0; r < 4; r++) rl[r] = 1.f / lacc[rt][r];
#pragma unroll
    for (int dt = 0; dt < 4; dt++)
#pragma unroll
      for (int r = 0; r < 4; r++) {
        const float v = O[rt][dt][r] * rl[r];
        const int n = q0 + rt * 16 + quad * 4 + r;
        const int d = dt * 16 + l15;
        const size_t idx = ((size_t)b * 1024 + n) * 768 + h * 64 + d;
        out[idx] = v;
        obf[idx] = f2bf(v);
      }
  }
}

// ---------------- in-place LayerNorm over 768 ----------------
__global__ __launch_bounds__(256) void ln_kernel(float* __restrict__ p,
                                                 const float* __restrict__ nw,
                                                 const float* __restrict__ nb) {
  __shared__ float red[2][4];
  const int row = blockIdx.x, tid = threadIdx.x;
  float* pr = p + (size_t)row * 768;
  const float x0 = pr[tid], x1 = pr[tid + 256], x2 = pr[tid + 512];
  float s = x0 + x1 + x2;
  float sq = x0 * x0 + x1 * x1 + x2 * x2;
#pragma unroll
  for (int m = 1; m < 64; m <<= 1) {
    s += __shfl_xor(s, m, 64);
    sq += __shfl_xor(sq, m, 64);
  }
  const int w = tid >> 6;
  if ((tid & 63) == 0) { red[0][w] = s; red[1][w] = sq; }
  __syncthreads();
  s = red[0][0] + red[0][1] + red[0][2] + red[0][3];
  sq = red[1][0] + red[1][1] + red[1][2] + red[1][3];
  const float mean = s * (1.0f / 768.0f);
  const float var = sq * (1.0f / 768.0f) - mean * mean;
  const float rstd = rsqrtf(var + 1e-5f);
  pr[tid]       = (x0 - mean) * rstd * nw[tid]       + nb[tid];
  pr[tid + 256] = (x1 - mean) * rstd * nw[tid + 256] + nb[tid + 256];
  pr[tid + 512] = (x2 - mean) * rstd * nw[tid + 512] + nb[tid + 512];
}

extern "C" void kernel_launch(void* const* d_in, const int* in_sizes, int n_in,
                              void* d_out, int out_size, void* d_ws, size_t ws_size,
                              hipStream_t stream) {
  (void)in_sizes; (void)n_in; (void)out_size; (void)ws_size;
  const float* x      = (const float*)d_in[0];
  const float* qkv_w  = (const float*)d_in[1];
  const float* qkv_b  = (const float*)d_in[2];
  const float* proj_w = (const float*)d_in[3];
  const float* proj_b = (const float*)d_in[4];
  const float* norm_w = (const float*)d_in[5];
  const float* norm_b = (const float*)d_in[6];
  const float* bank_k = (const float*)d_in[7];
  const float* bank_v = (const float*)d_in[8];

  char* ws = (char*)d_ws;
  u16* xbf   = (u16*)(ws + 0);           // 16384x768 bf16 = 25165824
  u16* obf   = (u16*)(ws + 0);           // aliases xbf (dead after gemm<0>)
  u16* qwbf  = (u16*)(ws + 25165824);    // 2304x768  = 3538944
  u16* pwbf  = (u16*)(ws + 28704768);    // 768x768   = 1179648
  u16* bkbf  = (u16*)(ws + 29884416);    // 12x256x64 = 393216
  u16* bvtbf = (u16*)(ws + 30277632);    // 12x64x256 = 393216
  u16* q_ws  = (u16*)(ws + 30670848);    // 192x1024x64 = 25165824
  u16* k_ws  = (u16*)(ws + 55836672);
  u16* vt_ws = (u16*)(ws + 81002496);    // ends 106168320

  float* out0  = (float*)d_out;
  float* p_out = out0 + 12582912;        // second output region doubles as p scratch

  cvt_all_kernel<<<15360, 256, 0, stream>>>(x, qkv_w, proj_w, bank_k, bank_v,
                                            xbf, qwbf, pwbf, bkbf, bvtbf);

  gemm256<0><<<dim3(576), 512, 0, stream>>>(xbf, qwbf, qkv_b, q_ws, k_ws, vt_ws, nullptr);
  fa_kernel<<<dim3(192, 8), 256, 0, stream>>>(q_ws, k_ws, vt_ws, bkbf, bvtbf, out0, obf);
  gemm256<1><<<dim3(192), 512, 0, stream>>>(obf, pwbf, proj_b, nullptr, nullptr, nullptr, p_out);
  ln_kernel<<<16384, 256, 0, stream>>>(p_out, norm_w, norm_b);
}

// Round 4
// 405.372 us; speedup vs baseline: 1.7253x; 1.7253x over previous
//
#include <hip/hip_runtime.h>

typedef __attribute__((ext_vector_type(8))) short short8;
typedef __attribute__((ext_vector_type(4))) float float4_t;
typedef unsigned short u16;

#define K_DIM 768

__device__ __forceinline__ u16 f2bf(float f) {
  union { float f; unsigned u; } v; v.f = f;
  unsigned r = v.u + 0x7FFFu + ((v.u >> 16) & 1u);
  return (u16)(r >> 16);
}

__device__ __forceinline__ u16 f2bf_trunc(float f) {
  union { float f; unsigned u; } v; v.f = f;
  return (u16)(v.u >> 16);
}

__device__ __forceinline__ void gload16(const void* g, void* l) {
  __builtin_amdgcn_global_load_lds(
      (__attribute__((address_space(1))) void*)g,
      (__attribute__((address_space(3))) void*)l, 16, 0, 0);
}

// ---------------- fused fp32->bf16 converts + bank re-layout ----------------
__global__ __launch_bounds__(256) void cvt_all_kernel(
    const float* __restrict__ x, const float* __restrict__ qw,
    const float* __restrict__ pw, const float* __restrict__ bkf,
    const float* __restrict__ bvf,
    u16* __restrict__ xbf, u16* __restrict__ qwbf, u16* __restrict__ pwbf,
    u16* __restrict__ bk, u16* __restrict__ bvt) {
  const int blk = blockIdx.x;
  if (blk < 14592) {
    int i = blk * 256 + threadIdx.x;
    const float* src; u16* dst;
    if (i < 3145728)      { src = x;  dst = xbf; }
    else if (i < 3588096) { src = qw; dst = qwbf; i -= 3145728; }
    else                  { src = pw; dst = pwbf; i -= 3588096; }
    float4 v = ((const float4*)src)[i];
    union { u16 h[4]; unsigned long long ll; } o;
    o.h[0] = f2bf(v.x); o.h[1] = f2bf(v.y); o.h[2] = f2bf(v.z); o.h[3] = f2bf(v.w);
    ((unsigned long long*)dst)[i] = o.ll;
  } else {
    int idx = (blk - 14592) * 256 + threadIdx.x;  // < 196608
    int m = idx / 768;
    int c = idx - m * 768;
    int h = c >> 6, d = c & 63;
    bk[(h * 256 + m) * 64 + d] = f2bf(bkf[idx]);
    bvt[(h * 64 + d) * 256 + m] = f2bf(bvf[idx]);
  }
}

// ---------------- 256x256x64 8-phase bf16 GEMM, C = A * B^T ----------------
// (unchanged; its counters surface once fa drops below it)

#define SBAR()                                 \
  do {                                         \
    __builtin_amdgcn_sched_barrier(0);         \
    __builtin_amdgcn_s_barrier();              \
    __builtin_amdgcn_sched_barrier(0);         \
  } while (0)

#define VMW2()                                                  \
  do {                                                          \
    __builtin_amdgcn_sched_barrier(0);                          \
    asm volatile("s_waitcnt vmcnt(2)" ::: "memory");            \
  } while (0)

#define VMW0()                                                  \
  do {                                                          \
    __builtin_amdgcn_sched_barrier(0);                          \
    asm volatile("s_waitcnt vmcnt(0)" ::: "memory");            \
  } while (0)

#define LDA(B_, MH)                                                            \
  _Pragma("unroll") for (int m_ = 0; m_ < 4; m_++) {                           \
    const char* p_ =                                                           \
        (const char*)As[B_] + ((wm * 128 + (MH) * 64 + m_ * 16) << 7);         \
    af[m_][0] = *(const short8*)(p_ + ab0);                                    \
    af[m_][1] = *(const short8*)(p_ + ab1);                                    \
  }

#define LDB(B_, NH, BF)                                                        \
  _Pragma("unroll") for (int n_ = 0; n_ < 2; n_++) {                           \
    const char* p_ =                                                           \
        (const char*)Bs[B_] + ((wn * 64 + (NH) * 32 + n_ * 16) << 7);          \
    BF[n_][0] = *(const short8*)(p_ + ab0);                                    \
    BF[n_][1] = *(const short8*)(p_ + ab1);                                    \
  }

#define MFMAQ(MH, NH, BF)                                                      \
  do {                                                                         \
    __builtin_amdgcn_s_setprio(1);                                             \
    _Pragma("unroll") for (int m_ = 0; m_ < 4; m_++)                           \
        _Pragma("unroll") for (int n_ = 0; n_ < 2; n_++) {                     \
      acc[(MH) * 4 + m_][(NH) * 2 + n_] =                                      \
          __builtin_amdgcn_mfma_f32_16x16x32_bf16(                             \
              af[m_][0], BF[n_][0], acc[(MH) * 4 + m_][(NH) * 2 + n_], 0, 0,   \
              0);                                                              \
      acc[(MH) * 4 + m_][(NH) * 2 + n_] =                                      \
          __builtin_amdgcn_mfma_f32_16x16x32_bf16(                             \
              af[m_][1], BF[n_][1], acc[(MH) * 4 + m_][(NH) * 2 + n_], 0, 0,   \
              0);                                                              \
    }                                                                          \
    __builtin_amdgcn_s_setprio(0);                                             \
  } while (0)

template <int MODE>
__global__ __launch_bounds__(512, 2) void gemm256(
    const u16* __restrict__ A, const u16* __restrict__ Bw,
    const float* __restrict__ bias,
    u16* __restrict__ q_ws, u16* __restrict__ k_ws, u16* __restrict__ vt_ws,
    float* __restrict__ p_out) {
  __shared__ u16 As[2][16384];   // [buf][256 rows x 64 cols], 128B rows
  __shared__ u16 Bs[2][16384];
  const int tid = threadIdx.x;
  const int w = tid >> 6, lane = tid & 63;
  const int l15 = lane & 15, quad = lane >> 4;
  const int wm = w >> 2, wn = w & 3;

  constexpr int NBN = (MODE == 0) ? 9 : 3;
  const int bid = blockIdx.x;
  const int xcd = bid & 7, local = bid >> 3;   // nwg % 8 == 0 -> bijective
  const int bm = xcd * 8 + local / NBN;
  const int bn = local % NBN;

  // staging constants: linear LDS dest + inverse-swizzled global source.
  int soff[2], loff[2];
#pragma unroll
  for (int r = 0; r < 2; r++) {
    const int off = r * 8192 + tid * 16;     // byte in 16KB unit
    const int row = off >> 7;                // 128B per row (64 bf16)
    const int grp = (off & 127) >> 4;        // phys 16B slot 0..7
    soff[r] = row * K_DIM + ((grp ^ (row & 7)) * 8);
    loff[r] = off;
  }
  const u16* Abase = A + (size_t)bm * 256 * K_DIM;
  const u16* Bbase = Bw + (size_t)bn * 256 * K_DIM;

  auto stg = [&](const u16* g0, u16* l0) {
    gload16(g0 + soff[0], (char*)l0 + loff[0]);
    gload16(g0 + soff[1], (char*)l0 + loff[1]);
  };

  // ds-read swizzle constants: row&7 == l15&7 for all frag rows.
  const int ab0 = l15 * 128 + (((0 * 4 + quad) ^ (l15 & 7)) << 4);
  const int ab1 = l15 * 128 + (((1 * 4 + quad) ^ (l15 & 7)) << 4);

  float4_t acc[8][4];
#pragma unroll
  for (int i = 0; i < 8; i++)
#pragma unroll
    for (int j = 0; j < 4; j++) acc[i][j] = (float4_t){0.f, 0.f, 0.f, 0.f};

  short8 af[4][2], bf0[2][2], bf1[2][2];

  // ---- prologue: tile0 all 4 units + tile1 A0; wait tile0 ----
  stg(Abase, &As[0][0]);
  stg(Abase + 128 * K_DIM, &As[0][8192]);
  stg(Bbase, &Bs[0][0]);
  stg(Bbase + 128 * K_DIM, &Bs[0][8192]);
  stg(Abase + 64, &As[1][0]);
  VMW2();
  SBAR();

  // ---- main loop: groups 0..4, tiles 2g (buf0) and 2g+1 (buf1) ----
#pragma unroll 1
  for (int g = 0; g < 5; g++) {
    const int kt_o = g * 128 + 64;
    const int kt_p = g * 128 + 128;
    const int kt_q = g * 128 + 192;
    // P1: quadrant (mh0,nh0) of even tile; stage odd A1
    LDA(0, 0); LDB(0, 0, bf0);
    stg(Abase + 128 * K_DIM + kt_o, &As[1][8192]);
    SBAR(); MFMAQ(0, 0, bf0); SBAR();
    // P2: (mh0,nh1); stage odd B0
    LDB(0, 1, bf1);
    stg(Bbase + kt_o, &Bs[1][0]);
    SBAR(); MFMAQ(0, 1, bf1); SBAR();
    // P3: (mh1,nh1); stage odd B1   [last ds_read of buf0]
    LDA(0, 1);
    stg(Bbase + 128 * K_DIM + kt_o, &Bs[1][8192]);
    SBAR(); MFMAQ(1, 1, bf1); SBAR();
    // P4: (mh1,nh0); stage tile p A0 into buf0; wait odd tile complete
    stg(Abase + kt_p, &As[0][0]);
    VMW2(); SBAR(); MFMAQ(1, 0, bf0); SBAR();
    // P5: odd tile (mh0,nh0); stage p A1
    LDA(1, 0); LDB(1, 0, bf0);
    stg(Abase + 128 * K_DIM + kt_p, &As[0][8192]);
    SBAR(); MFMAQ(0, 0, bf0); SBAR();
    // P6: (mh0,nh1); stage p B0
    LDB(1, 1, bf1);
    stg(Bbase + kt_p, &Bs[0][0]);
    SBAR(); MFMAQ(0, 1, bf1); SBAR();
    // P7: (mh1,nh1); stage p B1   [last ds_read of buf1]
    LDA(1, 1);
    stg(Bbase + 128 * K_DIM + kt_p, &Bs[0][8192]);
    SBAR(); MFMAQ(1, 1, bf1); SBAR();
    // P8: (mh1,nh0); stage tile q A0 into buf1; wait tile p complete
    stg(Abase + kt_q, &As[1][0]);
    VMW2(); SBAR(); MFMAQ(1, 0, bf0); SBAR();
  }

  // ---- peeled last group: tiles 10 (buf0) and 11 (buf1) ----
  {
    const int kt_o = 704;
    LDA(0, 0); LDB(0, 0, bf0);
    stg(Abase + 128 * K_DIM + kt_o, &As[1][8192]);
    SBAR(); MFMAQ(0, 0, bf0); SBAR();
    LDB(0, 1, bf1);
    stg(Bbase + kt_o, &Bs[1][0]);
    SBAR(); MFMAQ(0, 1, bf1); SBAR();
    LDA(0, 1);
    stg(Bbase + 128 * K_DIM + kt_o, &Bs[1][8192]);
    SBAR(); MFMAQ(1, 1, bf1); SBAR();
    VMW0(); SBAR(); MFMAQ(1, 0, bf0); SBAR();
    LDA(1, 0); LDB(1, 0, bf0);
    SBAR(); MFMAQ(0, 0, bf0); SBAR();
    LDB(1, 1, bf1);
    SBAR(); MFMAQ(0, 1, bf1); SBAR();
    LDA(1, 1);
    SBAR(); MFMAQ(1, 1, bf1); SBAR();
    MFMAQ(1, 0, bf0);
  }

  // ---- epilogue ----
  const float QS = 0.18033688011112042f;  // (1/8) * log2(e)
#pragma unroll
  for (int mi = 0; mi < 8; mi++) {
#pragma unroll
    for (int ni = 0; ni < 4; ni++) {
      const int row0 = bm * 256 + wm * 128 + mi * 16 + quad * 4;
      const int f = bn * 256 + wn * 64 + ni * 16 + l15;
      const float bv = bias[f];
      if (MODE == 0) {
        const int which = f / 768;
        const int rem = f - which * 768;
        const int h = rem >> 6, d = rem & 63;
#pragma unroll
        for (int r2 = 0; r2 < 4; r2++) {
          float v = acc[mi][ni][r2] + bv;
          const int i = row0 + r2;
          const int bb = i >> 10, n = i & 1023;
          const size_t bhh = (size_t)(bb * 12 + h);
          if (which == 0)      q_ws[(bhh * 1024 + n) * 64 + d] = f2bf(v * QS);
          else if (which == 1) k_ws[(bhh * 1024 + n) * 64 + d] = f2bf(v);
          else                 vt_ws[(bhh * 64 + d) * 1024 + n] = f2bf(v);
        }
      } else {
#pragma unroll
        for (int r2 = 0; r2 < 4; r2++) {
          const int i = row0 + r2;
          p_out[(size_t)i * 768 + f] = acc[mi][ni][r2] + bv;
        }
      }
    }
  }
}

// ---------------- flash attention, double-buffered staging ----------------
// LDS 32 KB: smem[2][8192] = two K/V buffers (Ks 8KB + Vts 8KB each).
// Per iter t (cur = t&1): issue stage(t+1 -> cur^1) FIRST (stays in flight
// across the mid-barrier); compute QK from cur; pull V frags to regs;
// raw barrier + lgkmcnt(0) ONLY (no vmcnt drain!) -> P tiles alias cur's
// region (dead after kf/vf in regs); softmax+PV; end barrier with vmcnt(0)
// (staging loads had the whole iteration to land -> latency hidden).
// NOTE: no min-waves launch bound — forcing 4 waves/EU (<=128 regs) spilled
// ~60 regs to scratch (+720 MB HBM traffic, 3x slowdown) in round 3.
__global__ __launch_bounds__(256) void fa_kernel(
    const u16* __restrict__ qws, const u16* __restrict__ kws,
    const u16* __restrict__ vtws, const u16* __restrict__ bk,
    const u16* __restrict__ bvt,
    float* __restrict__ out, u16* __restrict__ obf) {
  __shared__ u16 smem[2][8192];      // 32 KB double buffer

  const int tid = threadIdx.x;
  const int w = tid >> 6, lane = tid & 63;
  const int l15 = lane & 15, quad = lane >> 4;
  const int bh = blockIdx.x;
  const int b = bh / 12, h = bh - b * 12;
  const int q0 = blockIdx.y * 128 + w * 32;

  short8 qf[2][2];
  {
    const u16* qb = qws + ((size_t)bh * 1024 + q0) * 64;
#pragma unroll
    for (int rt = 0; rt < 2; rt++)
#pragma unroll
      for (int c = 0; c < 2; c++)
        qf[rt][c] = *(const short8*)(qb + (rt * 16 + l15) * 64 + c * 32 + quad * 8);
  }

  const short ONE = (short)0x3F80;  // bf16 1.0
  const short8 onesf = (short8){ONE, ONE, ONE, ONE, ONE, ONE, ONE, ONE};

  float4_t O[2][4];
  float4_t lacc[2];
#pragma unroll
  for (int rt = 0; rt < 2; rt++) {
#pragma unroll
    for (int dt = 0; dt < 4; dt++) O[rt][dt] = (float4_t){0.f, 0.f, 0.f, 0.f};
    lacc[rt] = (float4_t){0.f, 0.f, 0.f, 0.f};
  }

  auto stage = [&](int tt, int buf) {
    const int mb = tt * 64;
    u16* Ksb = &smem[buf][0];
    u16* Vtb = &smem[buf][4096];
#pragma unroll
    for (int r = 0; r < 2; r++) {
      const int off = (w * 2 + r) * 1024 + lane * 16;
      const int row = off >> 7;             // 128B per row (64 bf16)
      const int grp = (off & 127) >> 4;     // 0..7
      const int lcol = (grp ^ (row & 7)) * 8;
      const u16* g = (mb < 1024)
          ? kws + ((size_t)bh * 1024 + mb + row) * 64 + lcol
          : bk + ((size_t)h * 256 + (mb - 1024) + row) * 64 + lcol;
      gload16(g, (char*)Ksb + off);
      const u16* g2 = (mb < 1024)
          ? vtws + ((size_t)bh * 64 + row) * 1024 + mb + lcol
          : bvt + ((size_t)h * 64 + row) * 256 + (mb - 1024) + lcol;
      gload16(g2, (char*)Vtb + off);
    }
  };

  // prologue: stage tile 0 into buf 0
  stage(0, 0);
  __builtin_amdgcn_sched_barrier(0);
  asm volatile("s_waitcnt vmcnt(0)" ::: "memory");
  __builtin_amdgcn_s_barrier();
  __builtin_amdgcn_sched_barrier(0);

#pragma unroll 1
  for (int t = 0; t < 20; t++) {
    const int cur = t & 1;
    // async prefetch of next K/V tile into the other buffer
    if (t < 19) stage(t + 1, cur ^ 1);

    const u16* Ks  = &smem[cur][0];
    const u16* Vts = &smem[cur][4096];
    u16* Psw = &smem[cur][0] + w * 2048;   // per-wave P tile, aliases cur

    short8 kf[4][2];
#pragma unroll
    for (int ct = 0; ct < 4; ct++)
#pragma unroll
      for (int c = 0; c < 2; c++) {
        const int row = ct * 16 + l15;
        kf[ct][c] = *(const short8*)(Ks + row * 64 + ((c * 4 + quad) ^ (row & 7)) * 8);
      }

    float4_t S[2][4];
#pragma unroll
    for (int rt = 0; rt < 2; rt++)
#pragma unroll
      for (int ct = 0; ct < 4; ct++) {
        float4_t z = (float4_t){0.f, 0.f, 0.f, 0.f};
        z = __builtin_amdgcn_mfma_f32_16x16x32_bf16(qf[rt][0], kf[ct][0], z, 0, 0, 0);
        S[rt][ct] = __builtin_amdgcn_mfma_f32_16x16x32_bf16(qf[rt][1], kf[ct][1], z, 0, 0, 0);
      }

    // V fragments into registers BEFORE P overwrites the cur region
    short8 vf[4][2];
#pragma unroll
    for (int dt = 0; dt < 4; dt++)
#pragma unroll
      for (int c = 0; c < 2; c++) {
        const int row = dt * 16 + l15;
        vf[dt][c] = *(const short8*)(Vts + row * 64 + ((c * 4 + quad) ^ (row & 7)) * 8);
      }

    // mid barrier: all waves' K/V reads of cur retired; staging loads
    // (vmcnt) deliberately NOT drained -> stay in flight.
    __builtin_amdgcn_sched_barrier(0);
    asm volatile("s_waitcnt lgkmcnt(0)" ::: "memory");
    __builtin_amdgcn_s_barrier();
    __builtin_amdgcn_sched_barrier(0);

    // exp2 + truncating bf16 pack -> aliased LDS (per-wave region)
#pragma unroll
    for (int rt = 0; rt < 2; rt++) {
#pragma unroll
      for (int ct = 0; ct < 4; ct++) {
        const int colg = ct * 2 + (l15 >> 3);
#pragma unroll
        for (int r = 0; r < 4; r++) {
          const float p = __builtin_amdgcn_exp2f(S[rt][ct][r]);
          const int q = rt * 16 + quad * 4 + r;
          Psw[q * 64 + (colg ^ (q & 7)) * 8 + (l15 & 7)] = f2bf_trunc(p);
        }
      }
    }

#pragma unroll
    for (int rt = 0; rt < 2; rt++)
#pragma unroll
      for (int c = 0; c < 2; c++) {
        const int qrow = rt * 16 + l15;
        const short8 pf = *(const short8*)(&Psw[qrow * 64 + (((c * 4 + quad) ^ (qrow & 7)) * 8)]);
#pragma unroll
        for (int dt = 0; dt < 4; dt++)
          O[rt][dt] = __builtin_amdgcn_mfma_f32_16x16x32_bf16(pf, vf[dt][c], O[rt][dt], 0, 0, 0);
        lacc[rt] = __builtin_amdgcn_mfma_f32_16x16x32_bf16(pf, onesf, lacc[rt], 0, 0, 0);
      }

    // end barrier: own staging loads landed (full iter to fly) + all P
    // writes/reads retired before next iter stages over this region.
    __builtin_amdgcn_sched_barrier(0);
    asm volatile("s_waitcnt vmcnt(0) lgkmcnt(0)" ::: "memory");
    __builtin_amdgcn_s_barrier();
    __builtin_amdgcn_sched_barrier(0);
  }

#pragma unroll
  for (int rt = 0; rt < 2; rt++) {
    float rl[4];
#pragma unroll
    for (int r = 0; r < 4; r++) rl[r] = 1.f / lacc[rt][r];
#pragma unroll
    for (int dt = 0; dt < 4; dt++)
#pragma unroll
      for (int r = 0; r < 4; r++) {
        const float v = O[rt][dt][r] * rl[r];
        const int n = q0 + rt * 16 + quad * 4 + r;
        const int d = dt * 16 + l15;
        const size_t idx = ((size_t)b * 1024 + n) * 768 + h * 64 + d;
        out[idx] = v;
        obf[idx] = f2bf(v);
      }
  }
}

// ---------------- in-place LayerNorm over 768 ----------------
__global__ __launch_bounds__(256) void ln_kernel(float* __restrict__ p,
                                                 const float* __restrict__ nw,
                                                 const float* __restrict__ nb) {
  __shared__ float red[2][4];
  const int row = blockIdx.x, tid = threadIdx.x;
  float* pr = p + (size_t)row * 768;
  const float x0 = pr[tid], x1 = pr[tid + 256], x2 = pr[tid + 512];
  float s = x0 + x1 + x2;
  float sq = x0 * x0 + x1 * x1 + x2 * x2;
#pragma unroll
  for (int m = 1; m < 64; m <<= 1) {
    s += __shfl_xor(s, m, 64);
    sq += __shfl_xor(sq, m, 64);
  }
  const int w = tid >> 6;
  if ((tid & 63) == 0) { red[0][w] = s; red[1][w] = sq; }
  __syncthreads();
  s = red[0][0] + red[0][1] + red[0][2] + red[0][3];
  sq = red[1][0] + red[1][1] + red[1][2] + red[1][3];
  const float mean = s * (1.0f / 768.0f);
  const float var = sq * (1.0f / 768.0f) - mean * mean;
  const float rstd = rsqrtf(var + 1e-5f);
  pr[tid]       = (x0 - mean) * rstd * nw[tid]       + nb[tid];
  pr[tid + 256] = (x1 - mean) * rstd * nw[tid + 256] + nb[tid + 256];
  pr[tid + 512] = (x2 - mean) * rstd * nw[tid + 512] + nb[tid + 512];
}

extern "C" void kernel_launch(void* const* d_in, const int* in_sizes, int n_in,
                              void* d_out, int out_size, void* d_ws, size_t ws_size,
                              hipStream_t stream) {
  (void)in_sizes; (void)n_in; (void)out_size; (void)ws_size;
  const float* x      = (const float*)d_in[0];
  const float* qkv_w  = (const float*)d_in[1];
  const float* qkv_b  = (const float*)d_in[2];
  const float* proj_w = (const float*)d_in[3];
  const float* proj_b = (const float*)d_in[4];
  const float* norm_w = (const float*)d_in[5];
  const float* norm_b = (const float*)d_in[6];
  const float* bank_k = (const float*)d_in[7];
  const float* bank_v = (const float*)d_in[8];

  char* ws = (char*)d_ws;
  u16* xbf   = (u16*)(ws + 0);           // 16384x768 bf16 = 25165824
  u16* obf   = (u16*)(ws + 0);           // aliases xbf (dead after gemm<0>)
  u16* qwbf  = (u16*)(ws + 25165824);    // 2304x768  = 3538944
  u16* pwbf  = (u16*)(ws + 28704768);    // 768x768   = 1179648
  u16* bkbf  = (u16*)(ws + 29884416);    // 12x256x64 = 393216
  u16* bvtbf = (u16*)(ws + 30277632);    // 12x64x256 = 393216
  u16* q_ws  = (u16*)(ws + 30670848);    // 192x1024x64 = 25165824
  u16* k_ws  = (u16*)(ws + 55836672);
  u16* vt_ws = (u16*)(ws + 81002496);    // ends 106168320

  float* out0  = (float*)d_out;
  float* p_out = out0 + 12582912;        // second output region doubles as p scratch

  cvt_all_kernel<<<15360, 256, 0, stream>>>(x, qkv_w, proj_w, bank_k, bank_v,
                                            xbf, qwbf, pwbf, bkbf, bvtbf);

  gemm256<0><<<dim3(576), 512, 0, stream>>>(xbf, qwbf, qkv_b, q_ws, k_ws, vt_ws, nullptr);
  fa_kernel<<<dim3(192, 8), 256, 0, stream>>>(q_ws, k_ws, vt_ws, bkbf, bvtbf, out0, obf);
  gemm256<1><<<dim3(192), 512, 0, stream>>>(obf, pwbf, proj_b, nullptr, nullptr, nullptr, p_out);
  ln_kernel<<<16384, 256, 0, stream>>>(p_out, norm_w, norm_b);
}

// Round 5
// 400.658 us; speedup vs baseline: 1.7456x; 1.0118x over previous
//
#include <hip/hip_runtime.h>

typedef __attribute__((ext_vector_type(8))) short short8;
typedef __attribute__((ext_vector_type(4))) float float4_t;
typedef unsigned short u16;

#define K_DIM 768

__device__ __forceinline__ u16 f2bf(float f) {
  union { float f; unsigned u; } v; v.f = f;
  unsigned r = v.u + 0x7FFFu + ((v.u >> 16) & 1u);
  return (u16)(r >> 16);
}

__device__ __forceinline__ u16 f2bf_trunc(float f) {
  union { float f; unsigned u; } v; v.f = f;
  return (u16)(v.u >> 16);
}

__device__ __forceinline__ void gload16(const void* g, void* l) {
  __builtin_amdgcn_global_load_lds(
      (__attribute__((address_space(1))) void*)g,
      (__attribute__((address_space(3))) void*)l, 16, 0, 0);
}

// ---------------- fused fp32->bf16 converts + bank re-layout ----------------
__global__ __launch_bounds__(256) void cvt_all_kernel(
    const float* __restrict__ x, const float* __restrict__ qw,
    const float* __restrict__ pw, const float* __restrict__ bkf,
    const float* __restrict__ bvf,
    u16* __restrict__ xbf, u16* __restrict__ qwbf, u16* __restrict__ pwbf,
    u16* __restrict__ bk, u16* __restrict__ bvt) {
  const int blk = blockIdx.x;
  if (blk < 14592) {
    int i = blk * 256 + threadIdx.x;
    const float* src; u16* dst;
    if (i < 3145728)      { src = x;  dst = xbf; }
    else if (i < 3588096) { src = qw; dst = qwbf; i -= 3145728; }
    else                  { src = pw; dst = pwbf; i -= 3588096; }
    float4 v = ((const float4*)src)[i];
    union { u16 h[4]; unsigned long long ll; } o;
    o.h[0] = f2bf(v.x); o.h[1] = f2bf(v.y); o.h[2] = f2bf(v.z); o.h[3] = f2bf(v.w);
    ((unsigned long long*)dst)[i] = o.ll;
  } else {
    int idx = (blk - 14592) * 256 + threadIdx.x;  // < 196608
    int m = idx / 768;
    int c = idx - m * 768;
    int h = c >> 6, d = c & 63;
    bk[(h * 256 + m) * 64 + d] = f2bf(bkf[idx]);
    bvt[(h * 64 + d) * 256 + m] = f2bf(bvf[idx]);
  }
}

// ---------------- 128x128x64 2-phase bf16 GEMM, C = A * B^T ----------------
// m228d structure (622 TF refcheck'd quadrant): 64 KB LDS double-buffer ->
// 2 blocks/CU (cross-block overlap covers the per-step vmcnt(0) drain);
// per K-step: issue STAGE(next) FIRST, ds_read 16 frags, 32 MFMA, one
// __syncthreads. No setprio (T5 null on 2-phase), no sched_barrier pinning
// (m141: pinning defeats the compiler's own fine-grained waitcnt schedule).
// Grid 1D + bijective XCD swizzle (nwg % 8 == 0): same-bm blocks share the
// A panel within one XCD's L2.
template <int MODE>
__global__ __launch_bounds__(256) void gemm128b(
    const u16* __restrict__ A, const u16* __restrict__ Bw,
    const float* __restrict__ bias,
    u16* __restrict__ q_ws, u16* __restrict__ k_ws, u16* __restrict__ vt_ws,
    float* __restrict__ p_out) {
  __shared__ u16 As[2][8192];   // [buf][128 rows x 64 cols], 128B rows, 16 KB
  __shared__ u16 Bs[2][8192];
  const int tid = threadIdx.x;
  const int w = tid >> 6, lane = tid & 63;
  const int l15 = lane & 15, quad = lane >> 4;
  const int wm = w >> 1, wn = w & 1;

  constexpr int NBN = (MODE == 0) ? 18 : 6;
  const int bid = blockIdx.x;
  const int xcd = bid & 7, local = bid >> 3;
  const int bm = xcd * 16 + local / NBN;   // [0,128)
  const int bn = local % NBN;

  // staging: linear LDS dest + inverse-XOR-swizzled global column.
  int soff[4], loff[4];
#pragma unroll
  for (int r = 0; r < 4; r++) {
    const int off = r * 4096 + tid * 16;   // byte offset in 16 KB tile
    const int row = off >> 7;              // 128 B per row (64 bf16)
    const int grp = (off & 127) >> 4;      // phys 16B group 0..7
    soff[r] = row * K_DIM + (grp ^ (row & 7)) * 8;
    loff[r] = off;
  }
  const u16* Abase = A + (size_t)bm * 128 * K_DIM;
  const u16* Bbase = Bw + (size_t)bn * 128 * K_DIM;

  auto stg = [&](const u16* g0, u16* l0, int kt) {
#pragma unroll
    for (int r = 0; r < 4; r++)
      gload16(g0 + soff[r] + kt, (char*)l0 + loff[r]);
  };

  // ds-read swizzle: frag rows have row&7 == l15&7.
  const int ab0 = l15 * 128 + ((quad ^ (l15 & 7)) << 4);        // k in [0,32)
  const int ab1 = l15 * 128 + (((4 + quad) ^ (l15 & 7)) << 4);  // k in [32,64)

  float4_t acc[4][4];
#pragma unroll
  for (int i = 0; i < 4; i++)
#pragma unroll
    for (int j = 0; j < 4; j++) acc[i][j] = (float4_t){0.f, 0.f, 0.f, 0.f};

  // prologue: stage K-tile 0 into buf 0
  stg(Abase, As[0], 0);
  stg(Bbase, Bs[0], 0);
  __syncthreads();

  int buf = 0;
#pragma unroll 1
  for (int t = 0; t < 12; t++) {
    // async prefetch of next K-tile (in flight across ds_read + MFMA)
    if (t < 11) {
      stg(Abase, As[buf ^ 1], (t + 1) * 64);
      stg(Bbase, Bs[buf ^ 1], (t + 1) * 64);
    }
    short8 af[4][2], bfr[4][2];
#pragma unroll
    for (int mt = 0; mt < 4; mt++) {
      const char* p = (const char*)As[buf] + ((wm * 64 + mt * 16) << 7);
      af[mt][0] = *(const short8*)(p + ab0);
      af[mt][1] = *(const short8*)(p + ab1);
    }
#pragma unroll
    for (int nt = 0; nt < 4; nt++) {
      const char* p = (const char*)Bs[buf] + ((wn * 64 + nt * 16) << 7);
      bfr[nt][0] = *(const short8*)(p + ab0);
      bfr[nt][1] = *(const short8*)(p + ab1);
    }
#pragma unroll
    for (int mt = 0; mt < 4; mt++)
#pragma unroll
      for (int nt = 0; nt < 4; nt++) {
        acc[mt][nt] = __builtin_amdgcn_mfma_f32_16x16x32_bf16(
            af[mt][0], bfr[nt][0], acc[mt][nt], 0, 0, 0);
        acc[mt][nt] = __builtin_amdgcn_mfma_f32_16x16x32_bf16(
            af[mt][1], bfr[nt][1], acc[mt][nt], 0, 0, 0);
      }
    __syncthreads();   // drains prefetch (vmcnt0) after MFMA covered it
    buf ^= 1;
  }

  // ---- epilogue ----
  const float QS = 0.18033688011112042f;  // (1/8) * log2(e)
#pragma unroll
  for (int mt = 0; mt < 4; mt++) {
#pragma unroll
    for (int nt = 0; nt < 4; nt++) {
      const int row0 = bm * 128 + wm * 64 + mt * 16 + quad * 4;
      const int f = bn * 128 + wn * 64 + nt * 16 + l15;
      const float bv = bias[f];
      if (MODE == 0) {
        const int which = f / 768;
        const int rem = f - which * 768;
        const int h = rem >> 6, d = rem & 63;
#pragma unroll
        for (int r2 = 0; r2 < 4; r2++) {
          float v = acc[mt][nt][r2] + bv;
          const int i = row0 + r2;
          const int bb = i >> 10, n = i & 1023;
          const size_t bhh = (size_t)(bb * 12 + h);
          if (which == 0)      q_ws[(bhh * 1024 + n) * 64 + d] = f2bf(v * QS);
          else if (which == 1) k_ws[(bhh * 1024 + n) * 64 + d] = f2bf(v);
          else                 vt_ws[(bhh * 64 + d) * 1024 + n] = f2bf(v);
        }
      } else {
#pragma unroll
        for (int r2 = 0; r2 < 4; r2++) {
          const int i = row0 + r2;
          p_out[(size_t)i * 768 + f] = acc[mt][nt][r2] + bv;
        }
      }
    }
  }
}

// ---------------- flash attention, double-buffered staging ----------------
// LDS 32 KB: smem[2][8192] = two K/V buffers (Ks 8KB + Vts 8KB each).
// Per iter t (cur = t&1): issue stage(t+1 -> cur^1) FIRST (stays in flight
// across the mid-barrier); compute QK from cur; pull V frags to regs;
// raw barrier + lgkmcnt(0) ONLY (no vmcnt drain!) -> P tiles alias cur's
// region (dead after kf/vf in regs); softmax+PV; end barrier with vmcnt(0)
// (staging loads had the whole iteration to land -> latency hidden).
// NOTE: no min-waves launch bound — forcing 4 waves/EU (<=128 regs) spilled
// ~60 regs to scratch (+720 MB HBM traffic, 3x slowdown) in round 3.
__global__ __launch_bounds__(256) void fa_kernel(
    const u16* __restrict__ qws, const u16* __restrict__ kws,
    const u16* __restrict__ vtws, const u16* __restrict__ bk,
    const u16* __restrict__ bvt,
    float* __restrict__ out, u16* __restrict__ obf) {
  __shared__ u16 smem[2][8192];      // 32 KB double buffer

  const int tid = threadIdx.x;
  const int w = tid >> 6, lane = tid & 63;
  const int l15 = lane & 15, quad = lane >> 4;
  const int bh = blockIdx.x;
  const int b = bh / 12, h = bh - b * 12;
  const int q0 = blockIdx.y * 128 + w * 32;

  short8 qf[2][2];
  {
    const u16* qb = qws + ((size_t)bh * 1024 + q0) * 64;
#pragma unroll
    for (int rt = 0; rt < 2; rt++)
#pragma unroll
      for (int c = 0; c < 2; c++)
        qf[rt][c] = *(const short8*)(qb + (rt * 16 + l15) * 64 + c * 32 + quad * 8);
  }

  const short ONE = (short)0x3F80;  // bf16 1.0
  const short8 onesf = (short8){ONE, ONE, ONE, ONE, ONE, ONE, ONE, ONE};

  float4_t O[2][4];
  float4_t lacc[2];
#pragma unroll
  for (int rt = 0; rt < 2; rt++) {
#pragma unroll
    for (int dt = 0; dt < 4; dt++) O[rt][dt] = (float4_t){0.f, 0.f, 0.f, 0.f};
    lacc[rt] = (float4_t){0.f, 0.f, 0.f, 0.f};
  }

  auto stage = [&](int tt, int buf) {
    const int mb = tt * 64;
    u16* Ksb = &smem[buf][0];
    u16* Vtb = &smem[buf][4096];
#pragma unroll
    for (int r = 0; r < 2; r++) {
      const int off = (w * 2 + r) * 1024 + lane * 16;
      const int row = off >> 7;             // 128B per row (64 bf16)
      const int grp = (off & 127) >> 4;     // 0..7
      const int lcol = (grp ^ (row & 7)) * 8;
      const u16* g = (mb < 1024)
          ? kws + ((size_t)bh * 1024 + mb + row) * 64 + lcol
          : bk + ((size_t)h * 256 + (mb - 1024) + row) * 64 + lcol;
      gload16(g, (char*)Ksb + off);
      const u16* g2 = (mb < 1024)
          ? vtws + ((size_t)bh * 64 + row) * 1024 + mb + lcol
          : bvt + ((size_t)h * 64 + row) * 256 + (mb - 1024) + lcol;
      gload16(g2, (char*)Vtb + off);
    }
  };

  // prologue: stage tile 0 into buf 0
  stage(0, 0);
  __builtin_amdgcn_sched_barrier(0);
  asm volatile("s_waitcnt vmcnt(0)" ::: "memory");
  __builtin_amdgcn_s_barrier();
  __builtin_amdgcn_sched_barrier(0);

#pragma unroll 1
  for (int t = 0; t < 20; t++) {
    const int cur = t & 1;
    // async prefetch of next K/V tile into the other buffer
    if (t < 19) stage(t + 1, cur ^ 1);

    const u16* Ks  = &smem[cur][0];
    const u16* Vts = &smem[cur][4096];
    u16* Psw = &smem[cur][0] + w * 2048;   // per-wave P tile, aliases cur

    short8 kf[4][2];
#pragma unroll
    for (int ct = 0; ct < 4; ct++)
#pragma unroll
      for (int c = 0; c < 2; c++) {
        const int row = ct * 16 + l15;
        kf[ct][c] = *(const short8*)(Ks + row * 64 + ((c * 4 + quad) ^ (row & 7)) * 8);
      }

    float4_t S[2][4];
#pragma unroll
    for (int rt = 0; rt < 2; rt++)
#pragma unroll
      for (int ct = 0; ct < 4; ct++) {
        float4_t z = (float4_t){0.f, 0.f, 0.f, 0.f};
        z = __builtin_amdgcn_mfma_f32_16x16x32_bf16(qf[rt][0], kf[ct][0], z, 0, 0, 0);
        S[rt][ct] = __builtin_amdgcn_mfma_f32_16x16x32_bf16(qf[rt][1], kf[ct][1], z, 0, 0, 0);
      }

    // V fragments into registers BEFORE P overwrites the cur region
    short8 vf[4][2];
#pragma unroll
    for (int dt = 0; dt < 4; dt++)
#pragma unroll
      for (int c = 0; c < 2; c++) {
        const int row = dt * 16 + l15;
        vf[dt][c] = *(const short8*)(Vts + row * 64 + ((c * 4 + quad) ^ (row & 7)) * 8);
      }

    // mid barrier: all waves' K/V reads of cur retired; staging loads
    // (vmcnt) deliberately NOT drained -> stay in flight.
    __builtin_amdgcn_sched_barrier(0);
    asm volatile("s_waitcnt lgkmcnt(0)" ::: "memory");
    __builtin_amdgcn_s_barrier();
    __builtin_amdgcn_sched_barrier(0);

    // exp2 + truncating bf16 pack -> aliased LDS (per-wave region)
#pragma unroll
    for (int rt = 0; rt < 2; rt++) {
#pragma unroll
      for (int ct = 0; ct < 4; ct++) {
        const int colg = ct * 2 + (l15 >> 3);
#pragma unroll
        for (int r = 0; r < 4; r++) {
          const float p = __builtin_amdgcn_exp2f(S[rt][ct][r]);
          const int q = rt * 16 + quad * 4 + r;
          Psw[q * 64 + (colg ^ (q & 7)) * 8 + (l15 & 7)] = f2bf_trunc(p);
        }
      }
    }

#pragma unroll
    for (int rt = 0; rt < 2; rt++)
#pragma unroll
      for (int c = 0; c < 2; c++) {
        const int qrow = rt * 16 + l15;
        const short8 pf = *(const short8*)(&Psw[qrow * 64 + (((c * 4 + quad) ^ (qrow & 7)) * 8)]);
#pragma unroll
        for (int dt = 0; dt < 4; dt++)
          O[rt][dt] = __builtin_amdgcn_mfma_f32_16x16x32_bf16(pf, vf[dt][c], O[rt][dt], 0, 0, 0);
        lacc[rt] = __builtin_amdgcn_mfma_f32_16x16x32_bf16(pf, onesf, lacc[rt], 0, 0, 0);
      }

    // end barrier: own staging loads landed (full iter to fly) + all P
    // writes/reads retired before next iter stages over this region.
    __builtin_amdgcn_sched_barrier(0);
    asm volatile("s_waitcnt vmcnt(0) lgkmcnt(0)" ::: "memory");
    __builtin_amdgcn_s_barrier();
    __builtin_amdgcn_sched_barrier(0);
  }

#pragma unroll
  for (int rt = 0; rt < 2; rt++) {
    float rl[4];
#pragma unroll
    for (int r = 0; r < 4; r++) rl[r] = 1.f / lacc[rt][r];
#pragma unroll
    for (int dt = 0; dt < 4; dt++)
#pragma unroll
      for (int r = 0; r < 4; r++) {
        const float v = O[rt][dt][r] * rl[r];
        const int n = q0 + rt * 16 + quad * 4 + r;
        const int d = dt * 16 + l15;
        const size_t idx = ((size_t)b * 1024 + n) * 768 + h * 64 + d;
        out[idx] = v;
        obf[idx] = f2bf(v);
      }
  }
}

// ---------------- in-place LayerNorm over 768 ----------------
__global__ __launch_bounds__(256) void ln_kernel(float* __restrict__ p,
                                                 const float* __restrict__ nw,
                                                 const float* __restrict__ nb) {
  __shared__ float red[2][4];
  const int row = blockIdx.x, tid = threadIdx.x;
  float* pr = p + (size_t)row * 768;
  const float x0 = pr[tid], x1 = pr[tid + 256], x2 = pr[tid + 512];
  float s = x0 + x1 + x2;
  float sq = x0 * x0 + x1 * x1 + x2 * x2;
#pragma unroll
  for (int m = 1; m < 64; m <<= 1) {
    s += __shfl_xor(s, m, 64);
    sq += __shfl_xor(sq, m, 64);
  }
  const int w = tid >> 6;
  if ((tid & 63) == 0) { red[0][w] = s; red[1][w] = sq; }
  __syncthreads();
  s = red[0][0] + red[0][1] + red[0][2] + red[0][3];
  sq = red[1][0] + red[1][1] + red[1][2] + red[1][3];
  const float mean = s * (1.0f / 768.0f);
  const float var = sq * (1.0f / 768.0f) - mean * mean;
  const float rstd = rsqrtf(var + 1e-5f);
  pr[tid]       = (x0 - mean) * rstd * nw[tid]       + nb[tid];
  pr[tid + 256] = (x1 - mean) * rstd * nw[tid + 256] + nb[tid + 256];
  pr[tid + 512] = (x2 - mean) * rstd * nw[tid + 512] + nb[tid + 512];
}

extern "C" void kernel_launch(void* const* d_in, const int* in_sizes, int n_in,
                              void* d_out, int out_size, void* d_ws, size_t ws_size,
                              hipStream_t stream) {
  (void)in_sizes; (void)n_in; (void)out_size; (void)ws_size;
  const float* x      = (const float*)d_in[0];
  const float* qkv_w  = (const float*)d_in[1];
  const float* qkv_b  = (const float*)d_in[2];
  const float* proj_w = (const float*)d_in[3];
  const float* proj_b = (const float*)d_in[4];
  const float* norm_w = (const float*)d_in[5];
  const float* norm_b = (const float*)d_in[6];
  const float* bank_k = (const float*)d_in[7];
  const float* bank_v = (const float*)d_in[8];

  char* ws = (char*)d_ws;
  u16* xbf   = (u16*)(ws + 0);           // 16384x768 bf16 = 25165824
  u16* obf   = (u16*)(ws + 0);           // aliases xbf (dead after gemm<0>)
  u16* qwbf  = (u16*)(ws + 25165824);    // 2304x768  = 3538944
  u16* pwbf  = (u16*)(ws + 28704768);    // 768x768   = 1179648
  u16* bkbf  = (u16*)(ws + 29884416);    // 12x256x64 = 393216
  u16* bvtbf = (u16*)(ws + 30277632);    // 12x64x256 = 393216
  u16* q_ws  = (u16*)(ws + 30670848);    // 192x1024x64 = 25165824
  u16* k_ws  = (u16*)(ws + 55836672);
  u16* vt_ws = (u16*)(ws + 81002496);    // ends 106168320

  float* out0  = (float*)d_out;
  float* p_out = out0 + 12582912;        // second output region doubles as p scratch

  cvt_all_kernel<<<15360, 256, 0, stream>>>(x, qkv_w, proj_w, bank_k, bank_v,
                                            xbf, qwbf, pwbf, bkbf, bvtbf);

  gemm128b<0><<<dim3(2304), 256, 0, stream>>>(xbf, qwbf, qkv_b, q_ws, k_ws, vt_ws, nullptr);
  fa_kernel<<<dim3(192, 8), 256, 0, stream>>>(q_ws, k_ws, vt_ws, bkbf, bvtbf, out0, obf);
  gemm128b<1><<<dim3(768), 256, 0, stream>>>(obf, pwbf, proj_b, nullptr, nullptr, nullptr, p_out);
  ln_kernel<<<16384, 256, 0, stream>>>(p_out, norm_w, norm_b);
}